// Round 6
// baseline (566.394 us; speedup 1.0000x reference)
//
#include <hip/hip_runtime.h>
#include <math.h>

// WLN regressor, bf16-MFMA + register-resident gather (v6).
//  - gather commutes with row-wise matmul: gather(X)@W == gather(X@W)
//  - kernel (W_na/W_sa path) only live at last depth; U1 update dead after depth 1
//  - GEMMs: MFMA 16x16x32 bf16, XCD-swizzled (unchanged from R5)
//  - gather v6: NO LDS, NO DMA. Bond-projection weights hoisted to VGPRs
//    (lane l holds h=8l..8l+7 of all 6 weight rows); all indices for the
//    wave's 4 nodes loaded upfront; each neighbor row = one 40-lane dwordx4
//    into registers; issue pass fully decoupled from consume pass.

typedef unsigned short ushort_t;
typedef __attribute__((ext_vector_type(8))) short bf16x8;
typedef __attribute__((ext_vector_type(8))) unsigned short ushort8;
typedef __attribute__((ext_vector_type(4))) float f32x4;

static constexpr int Hh  = 300;
static constexpr int Hp  = 320;      // padded hidden (col dim & activation stride)
static constexpr int Bn  = 16;
static constexpr int Nn  = 2048;
static constexpr int Mm  = 4096;
static constexpr int Rn  = Bn * Nn;  // 32768 rows
static constexpr int NBn = 10;

// weight-region offsets (in ushorts, relative to wAf)
static constexpr size_t OFF_U2 = 320 * 96;
static constexpr size_t OFF_NA = OFF_U2 + 320 * 320;
static constexpr size_t OFF_SA = OFF_NA + 320 * 320;
static constexpr size_t OFF_U1 = OFF_SA + 320 * 320;
static constexpr int    W_ELEMS = (int)(OFF_U1 + 320 * 640);

__device__ __forceinline__ ushort_t f2bf(float x) {
    union { float f; unsigned u; } c; c.f = x;
    unsigned r = c.u + 0x7FFFu + ((c.u >> 16) & 1u);   // RNE
    return (ushort_t)(r >> 16);
}
__device__ __forceinline__ float bf2f(ushort_t h) {
    union { float f; unsigned u; } c; c.u = ((unsigned)h) << 16;
    return c.f;
}

// ---------------------------------------------------------------------------
// MFMA GEMM (unchanged from R5): C[r,n] = act(sum_k Asel[r,k]*Wt[n,k] (+bias))
// BM=256, BN=64, BK=32; 256 threads = 4 waves; 640 blocks XCD-swizzled.
// ---------------------------------------------------------------------------
template<bool RELU, bool BIAS, bool CONCAT>
__global__ __launch_bounds__(256)
void mfma_gemm_k(const ushort_t* __restrict__ A, const ushort_t* __restrict__ A2,
                 int lda, int KP,
                 const ushort_t* __restrict__ Wt,
                 const float* __restrict__ bias,
                 ushort_t* __restrict__ C)
{
    __shared__ __attribute__((aligned(16))) ushort_t As[256 * 40];
    __shared__ __attribute__((aligned(16))) ushort_t Bs[64 * 40];

    // XCD swizzle: 640 blocks = 8 xcd * (2 batch * 8 rowtile * 5 col)
    const int id   = blockIdx.x;
    const int xcd  = id & 7;
    const int slot = id >> 3;            // 0..79
    const int bsel = slot / 40;          // 0..1
    const int sub  = slot % 40;
    const int batch = xcd + 8 * bsel;    // 0..15
    const int rowBase = (batch * 8 + sub / 5) * 256;
    const int nBase   = (sub % 5) * 64;

    const int t   = threadIdx.x;
    const int wv  = t >> 6;
    const int ln  = t & 63;
    const int lrow = ln & 15;
    const int lgrp = ln >> 4;

    f32x4 acc[4][4];
#pragma unroll
    for (int i = 0; i < 4; i++)
#pragma unroll
        for (int j = 0; j < 4; j++) acc[i][j] = (f32x4){0.f, 0.f, 0.f, 0.f};

    const int half = KP >> 1;

    for (int k0 = 0; k0 < KP; k0 += 32) {
#pragma unroll
        for (int e = 0; e < 4; e++) {
            int chunk = t + e * 256;
            int r = chunk >> 2, c = chunk & 3;
            int k = k0 + c * 8;
            const ushort_t* src;
            if (CONCAT && k >= half) src = A2 + (size_t)(rowBase + r) * lda + (k - half);
            else                     src = A  + (size_t)(rowBase + r) * lda + k;
            *(ushort8*)&As[r * 40 + c * 8] = *(const ushort8*)src;
        }
        {
            int r = t >> 2, c = t & 3;
            *(ushort8*)&Bs[r * 40 + c * 8] =
                *(const ushort8*)(Wt + (size_t)(nBase + r) * KP + k0 + c * 8);
        }
        __syncthreads();

        bf16x8 af[4], bfr[4];
#pragma unroll
        for (int mb = 0; mb < 4; mb++)
            af[mb] = *(const bf16x8*)&As[(wv * 64 + mb * 16 + lrow) * 40 + lgrp * 8];
#pragma unroll
        for (int nb = 0; nb < 4; nb++)
            bfr[nb] = *(const bf16x8*)&Bs[(nb * 16 + lrow) * 40 + lgrp * 8];
#pragma unroll
        for (int mb = 0; mb < 4; mb++)
#pragma unroll
            for (int nb = 0; nb < 4; nb++)
                acc[mb][nb] = __builtin_amdgcn_mfma_f32_16x16x32_bf16(
                    af[mb], bfr[nb], acc[mb][nb], 0, 0, 0);
        __syncthreads();
    }

    // epilogue: D layout col=lane&15, row=(lane>>4)*4+r
#pragma unroll
    for (int mb = 0; mb < 4; mb++) {
        int row0 = rowBase + wv * 64 + mb * 16 + lgrp * 4;
#pragma unroll
        for (int nb = 0; nb < 4; nb++) {
            int col = nBase + nb * 16 + lrow;
            float bv = 0.f;
            if (BIAS) bv = (col < Hh) ? bias[col] : 0.f;
#pragma unroll
            for (int r = 0; r < 4; r++) {
                float v = acc[mb][nb][r] + bv;
                if (RELU) v = v > 0.f ? v : 0.f;
                C[(size_t)(row0 + r) * Hp + col] = f2bf(v);
            }
        }
    }
}

// ---------------------------------------------------------------------------
// Gather v6. 2048 blocks (XCD-swizzled) x 4 waves x 4 nodes/wave. No LDS.
// lane l<40 owns h = 8l..8l+7. Weights (6x300) + bias/Wout hoisted to VGPRs.
// Per node: 1 bond vector-load (60 lanes), <=10 independent dwordx4 row loads
// into named registers, then a pure-VALU consume pass.
// ---------------------------------------------------------------------------
template<bool FINAL>
__global__ __launch_bounds__(256, 3)
void gather_k(const ushort_t* __restrict__ Arow,   // bf16 [R][320]
              const ushort_t* __restrict__ Asa,    // FINAL only
              const float* __restrict__ bond,      // [B*M, 6] fp32
              const float* __restrict__ Wb,        // 6 x 300 fp32
              const float* __restrict__ bias,      // b_u2 (LABEL)
              const int*   __restrict__ ag,
              const int*   __restrict__ bg,
              const int*   __restrict__ nnb,
              const float* __restrict__ nmask,     // FINAL
              const float* __restrict__ Wout,      // FINAL
              void* __restrict__ outp)             // bf16 label [R][320] or f32 out[B]
{
    const int lane = threadIdx.x & 63;
    const int wave = threadIdx.x >> 6;
    const int lc   = lane < 40 ? lane : 39;        // clamped row lane
    const int hbase = 8 * lc;

    // hoist bond-projection weights + bias/Wout into VGPRs (guarded scalar loads)
    float W[6][8], V[8];
#pragma unroll
    for (int t = 0; t < 6; t++)
#pragma unroll
        for (int j = 0; j < 8; j++) {
            int h = hbase + j;
            W[t][j] = (h < Hh) ? Wb[t * Hh + h] : 0.f;
        }
#pragma unroll
    for (int j = 0; j < 8; j++) {
        int h = hbase + j;
        float v = 0.f;
        if (h < Hh) v = FINAL ? Wout[h] : bias[h];
        V[j] = v;
    }

    // XCD swizzle: 2048 blocks = 8 xcd * (2 batch * 128 groups)
    const int id   = blockIdx.x;
    const int xcd  = id & 7;
    const int slot = id >> 3;                  // 0..255
    const int b    = xcd + 8 * (slot & 1);     // batch -> XCD b%8
    const int grp  = slot >> 1;                // 0..127
    const int node0 = b * Nn + grp * 16 + wave * 4;

    const size_t arow0 = (size_t)b * Nn * Hp;
    const size_t brow0 = (size_t)b * Mm * 6;

    // upfront indices for this wave's 4 nodes (lanes 0..39)
    const int iav = ag[node0 * NBn + lc];
    const int ibv = bg[node0 * NBn + lc];
    const int nv  = nnb[node0 + (lane < 4 ? lane : 3)];

    const int l6 = (lane < 60) ? lane / 6 : 9; // bond slot per lane
    const int r6 = (lane < 60) ? lane - 6 * l6 : 0;

    float dotsum = 0.f;

#pragma unroll 1
    for (int g = 0; g < 4; g++) {
        const int node = node0 + g;
        const int nn   = __builtin_amdgcn_readfirstlane(__shfl(nv, g));

        // bond scalars for all 10 slots in one load: lane 6k+t -> bond[bg_k][t]
        int bk = __shfl(ibv, g * 10 + l6);
        float bondv = bond[brow0 + (size_t)bk * 6 + r6];

        // ---- issue pass: all row loads, independent ----
        ushort8 rowA[NBn];
#pragma unroll
        for (int k = 0; k < NBn; k++) {
            if (k < nn) {
                int iak = __shfl(iav, g * 10 + k);
                rowA[k] = *(const ushort8*)(Arow + arow0 + (size_t)iak * Hp + hbase);
            }
        }
        ushort8 rowS;
        if (FINAL)
            rowS = *(const ushort8*)(Asa + (size_t)node * Hp + hbase);

        // ---- consume pass: pure VALU ----
        float acc[8] = {0.f, 0.f, 0.f, 0.f, 0.f, 0.f, 0.f, 0.f};
#pragma unroll
        for (int k = 0; k < NBn; k++) {
            if (k < nn) {
                float c0 = __shfl(bondv, 6 * k + 0);
                float c1 = __shfl(bondv, 6 * k + 1);
                float c2 = __shfl(bondv, 6 * k + 2);
                float c3 = __shfl(bondv, 6 * k + 3);
                float c4 = __shfl(bondv, 6 * k + 4);
                float c5 = __shfl(bondv, 6 * k + 5);
#pragma unroll
                for (int j = 0; j < 8; j++) {
                    float w = c0 * W[0][j] + c1 * W[1][j] + c2 * W[2][j]
                            + c3 * W[3][j] + c4 * W[4][j] + c5 * W[5][j];
                    float a = bf2f((ushort_t)rowA[k][j]);
                    if (FINAL) {
                        acc[j] += a * w;
                    } else {
                        float v = a + w + V[j];
                        acc[j] += v > 0.f ? v : 0.f;
                    }
                }
            }
        }

        if (FINAL) {
            float d = 0.f;
#pragma unroll
            for (int j = 0; j < 8; j++)
                d += acc[j] * bf2f((ushort_t)rowS[j]) * V[j];
            if (lane >= 40) d = 0.f;               // lanes 40..63 duplicate lane 39
            d *= nmask[node];
            dotsum += d;
        } else {
            ushort8 o;
#pragma unroll
            for (int j = 0; j < 8; j++) o[j] = f2bf(acc[j]);
            if (lane < 40) {
                ushort8* pl = (ushort8*)((ushort_t*)outp + (size_t)node * Hp + hbase);
                __builtin_nontemporal_store(o, pl);
            }
        }
    }

    if (FINAL) {
#pragma unroll
        for (int off = 32; off > 0; off >>= 1)
            dotsum += __shfl_down(dotsum, off, 64);
        if (lane == 0) atomicAdd(&((float*)outp)[b], dotsum);
    }
}

// ---------------------------------------------------------------------------
__global__ void zero_k(ushort_t* __restrict__ p, int n)
{
    int i = blockIdx.x * 256 + threadIdx.x;
    if (i < n) p[i] = 0;
}

__global__ void cvt_atom_k(const float* __restrict__ src, ushort_t* __restrict__ dst)
{
    int idx = blockIdx.x * 256 + threadIdx.x;    // over R*96
    if (idx >= Rn * 96) return;
    int r = idx / 96, c = idx - r * 96;
    dst[idx] = (c < 82) ? f2bf(src[r * 82 + c]) : (ushort_t)0;
}

// all weight conversions in one launch; grid.y selects segment
__global__ void cvt_weights_k(const float* __restrict__ W_af,
                              const float* __restrict__ W_u2,
                              const float* __restrict__ W_na,
                              const float* __restrict__ W_sa,
                              const float* __restrict__ W_u1,
                              ushort_t* __restrict__ dst0)
{
    const float* src; int Ksrc, kbase, stride; size_t doff;
    switch (blockIdx.y) {
    case 0:  src = W_af;             Ksrc =  82; kbase = 0;   stride =  96; doff = 0;      break;
    case 1:  src = W_u2;             Ksrc = 300; kbase = 0;   stride = 320; doff = OFF_U2; break;
    case 2:  src = W_na;             Ksrc = 300; kbase = 0;   stride = 320; doff = OFF_NA; break;
    case 3:  src = W_sa;             Ksrc = 300; kbase = 0;   stride = 320; doff = OFF_SA; break;
    case 4:  src = W_u1;             Ksrc = 300; kbase = 0;   stride = 640; doff = OFF_U1; break;
    default: src = W_u1 + 300 * 300; Ksrc = 300; kbase = 320; stride = 640; doff = OFF_U1; break;
    }
    int idx = blockIdx.x * 256 + threadIdx.x;
    if (idx >= Ksrc * Hh) return;
    int k = idx / Hh, n = idx - k * Hh;
    dst0[doff + (size_t)n * stride + kbase + k] = f2bf(src[idx]);
}

__global__ void init_out_k(float* __restrict__ out, const float* __restrict__ b_out)
{
    if (threadIdx.x < Bn) out[threadIdx.x] = b_out[0];
}

// ---------------------------------------------------------------------------
extern "C" void kernel_launch(void* const* d_in, const int* in_sizes, int n_in,
                              void* d_out, int out_size, void* d_ws, size_t ws_size,
                              hipStream_t stream)
{
    const float* input_atom = (const float*)d_in[0];
    const float* input_bond = (const float*)d_in[1];
    const float* node_mask  = (const float*)d_in[2];
    const int*   atom_graph = (const int*)d_in[3];
    const int*   bond_graph = (const int*)d_in[4];
    const int*   num_nbs    = (const int*)d_in[5];
    const float* W_af       = (const float*)d_in[6];
    const float* W_na       = (const float*)d_in[7];
    const float* W_nb       = (const float*)d_in[8];
    const float* W_sa       = (const float*)d_in[9];
    const float* W_u2       = (const float*)d_in[10];
    const float* b_u2       = (const float*)d_in[11];
    const float* W_u1       = (const float*)d_in[12];
    const float* b_u1       = (const float*)d_in[13];
    const float* W_out      = (const float*)d_in[14];
    const float* b_out      = (const float*)d_in[15];
    float* out = (float*)d_out;

    const float* W_u2b = W_u2 + (size_t)Hh * Hh;   // rows 300..305 (bond part)

    const size_t S2 = (size_t)Rn * Hp;             // bf16 elems per activation buffer
    ushort_t* bufA0 = (ushort_t*)d_ws;
    ushort_t* bufA1 = bufA0 + S2;
    ushort_t* bufP  = bufA1 + S2;                  // A_u2 / A_na projections
    ushort_t* bufL  = bufP  + S2;                  // nei_label
    ushort_t* bufS  = bufL  + S2;                  // A_sa
    ushort_t* iaB   = bufS  + S2;                  // input_atom bf16 [R][96]
    ushort_t* wAf   = iaB + (size_t)Rn * 96;       // weight region base

    zero_k<<<(W_ELEMS + 255) / 256, 256, 0, stream>>>(wAf, W_ELEMS);
    cvt_atom_k<<<(Rn * 96 + 255) / 256, 256, 0, stream>>>(input_atom, iaB);
    cvt_weights_k<<<dim3(352, 6), 256, 0, stream>>>(W_af, W_u2, W_na, W_sa, W_u1, wAf);
    init_out_k<<<dim3(1), dim3(64), 0, stream>>>(out, b_out);

    const int gemmBlocks = 640;                    // 8 xcd * 2 batch * 8 rt * 5 col
    const int gb = 2048;                           // gather blocks: 4 waves x 4 nodes

    mfma_gemm_k<true, false, false><<<gemmBlocks, 256, 0, stream>>>(
        iaB, nullptr, 96, 96, wAf, nullptr, bufA0);

    ushort_t* cur = bufA0;
    ushort_t* oth = bufA1;
    for (int d = 0; d < 2; d++) {
        mfma_gemm_k<false, false, false><<<gemmBlocks, 256, 0, stream>>>(
            cur, nullptr, Hp, Hp, wAf + OFF_U2, nullptr, bufP);
        gather_k<false><<<gb, 256, 0, stream>>>(
            bufP, nullptr, input_bond, W_u2b, b_u2,
            atom_graph, bond_graph, num_nbs, nullptr, nullptr, bufL);
        mfma_gemm_k<true, true, true><<<gemmBlocks, 256, 0, stream>>>(
            cur, bufL, Hp, 2 * Hp, wAf + OFF_U1, b_u1, oth);
        ushort_t* tmp = cur; cur = oth; oth = tmp;
    }

    // depth 2: only the kernel output is live
    mfma_gemm_k<false, false, false><<<gemmBlocks, 256, 0, stream>>>(
        cur, nullptr, Hp, Hp, wAf + OFF_NA, nullptr, bufP);
    mfma_gemm_k<false, false, false><<<gemmBlocks, 256, 0, stream>>>(
        cur, nullptr, Hp, Hp, wAf + OFF_SA, nullptr, bufS);
    gather_k<true><<<gb, 256, 0, stream>>>(
        bufP, bufS, input_bond, W_nb, nullptr,
        atom_graph, bond_graph, num_nbs, node_mask, W_out, out);
}